// Round 1
// baseline (136.589 us; speedup 1.0000x reference)
//
#include <hip/hip_runtime.h>

// Problem constants (from reference): B=16384, IN_DIM=1024, D=256, C=100
#define BATCH 16384
#define KDIM  1024
#define DDIM  256
#define CNUM  100
#define CPAD  112   // classes padded to multiple of 16 for MFMA

typedef __bf16 bf16x4 __attribute__((ext_vector_type(4)));
typedef __bf16 bf16x8 __attribute__((ext_vector_type(8)));
typedef float  floatx4 __attribute__((ext_vector_type(4)));

static __device__ __forceinline__ unsigned short f2b(float f) {
    return __builtin_bit_cast(unsigned short, (__bf16)f);
}

// ---------------- prep 1: W [K][D] fp32 -> Wt [D][K] bf16 (tiled transpose) --
__global__ __launch_bounds__(256) void prep_w(const float* __restrict__ W,
                                              unsigned short* __restrict__ Wt) {
    __shared__ float T[32][33];
    const int bid = blockIdx.x;
    const int k0 = (bid & 31) * 32;   // 32 k-tiles
    const int n0 = (bid >> 5) * 32;   // 8 n-tiles
    const int j  = threadIdx.x & 31;
    const int i0 = threadIdx.x >> 5;  // 0..7
#pragma unroll
    for (int l = 0; l < 4; ++l) {
        int i = i0 + l * 8;
        T[i][j] = W[(k0 + i) * DDIM + n0 + j];   // coalesced over j
    }
    __syncthreads();
#pragma unroll
    for (int l = 0; l < 4; ++l) {
        int i = i0 + l * 8;                       // i = n offset now
        Wt[(n0 + i) * KDIM + k0 + j] = f2b(T[j][i]);  // coalesced over j (=k)
    }
}

// ---------------- prep 2: P -> bf16 padded, pnorm2 fp32 ----------------------
__global__ __launch_bounds__(64) void prep_p(const float* __restrict__ P,
                                             unsigned short* __restrict__ Pbf,
                                             float* __restrict__ pnorm2) {
    const int c = blockIdx.x;
    const int lane = threadIdx.x;
    float s = 0.f;
#pragma unroll
    for (int jj = 0; jj < 4; ++jj) {
        int d = jj * 64 + lane;
        float v = (c < CNUM) ? P[c * DDIM + d] : 0.f;
        Pbf[c * DDIM + d] = f2b(v);
        s += v * v;
    }
#pragma unroll
    for (int m = 1; m < 64; m <<= 1) s += __shfl_xor(s, m, 64);
    if (lane == 0) pnorm2[c] = s;
}

// ---------------- fused main -------------------------------------------------
// grid = 256 blocks (BM=64 rows each), 512 threads = 8 waves.
// GEMM1: Z[64][256] = x_tile @ W + b  via 16x16x32 bf16 MFMA.
//   wave w: rowgroup rg=w>>1 (16 rows), col half ch=w&1 (128 cols, 8 frags).
// Epilogue: bias, rownorm2 (fp32), Z->LDS bf16, GEMM2: P @ Z^T (M=112,N=64),
//   out[b][c] = (2*G - ||Z||^2 - ||P||^2)/256.
__global__ __launch_bounds__(512) void fused_main(
    const float* __restrict__ x, const float* __restrict__ bias,
    const unsigned short* __restrict__ Wt, const unsigned short* __restrict__ Pbf,
    const float* __restrict__ pnorm2, float* __restrict__ out)
{
    __shared__ unsigned short As[64 * 40];    // A tile, row stride 40 (pad)
    __shared__ unsigned short Bs[256 * 40];   // B tile [n][k], stride 40
    __shared__ unsigned short Zs[64 * 264];   // Z bf16, row stride 264 (pad)
    __shared__ float rn2[2][64];              // partial row norms per col-half

    const int tid  = threadIdx.x;
    const int wave = tid >> 6;
    const int lane = tid & 63;
    const int lm   = lane & 15;
    const int lq   = lane >> 4;
    const int rg   = wave >> 1;   // 0..3
    const int ch   = wave & 1;    // 0..1
    const int r0   = blockIdx.x * 64;

    // staging assignment
    const int rowA = tid >> 3;            // 0..63 (row of x tile)
    const int kcA  = (tid & 7) * 4;       // k offset 0..28, float4 each
    const int nB   = tid >> 1;            // 0..255 (row of Wt)
    const int kb0  = (tid & 1) * 16;      // k half 0 or 16

    const float* gA = x + (r0 + rowA) * KDIM + kcA;
    const unsigned short* gB = Wt + nB * KDIM;

    floatx4 acc[8];
#pragma unroll
    for (int f = 0; f < 8; ++f) { acc[f][0]=0.f; acc[f][1]=0.f; acc[f][2]=0.f; acc[f][3]=0.f; }

    // prefetch k-step 0
    floatx4 pa = *(const floatx4*)(gA);
    bf16x8 pb0 = *(const bf16x8*)(gB + kb0);
    bf16x8 pb1 = *(const bf16x8*)(gB + kb0 + 8);

    for (int kk = 0; kk < KDIM; kk += 32) {
        __syncthreads();   // previous iter's frag reads complete
        bf16x4 ha;
        ha[0] = (__bf16)pa[0]; ha[1] = (__bf16)pa[1];
        ha[2] = (__bf16)pa[2]; ha[3] = (__bf16)pa[3];
        *(bf16x4*)&As[rowA * 40 + kcA] = ha;
        *(bf16x8*)&Bs[nB * 40 + kb0]     = pb0;
        *(bf16x8*)&Bs[nB * 40 + kb0 + 8] = pb1;
        __syncthreads();
        if (kk + 32 < KDIM) {   // prefetch next tile (latency hidden by MFMA)
            pa  = *(const floatx4*)(gA + kk + 32);
            pb0 = *(const bf16x8*)(gB + kk + 32 + kb0);
            pb1 = *(const bf16x8*)(gB + kk + 32 + kb0 + 8);
        }
        // A-frag: A[m=lm][k=lq*8+j]
        bf16x8 af = *(const bf16x8*)&As[(rg * 16 + lm) * 40 + lq * 8];
#pragma unroll
        for (int f = 0; f < 8; ++f) {
            // B-frag: B[k=lq*8+j][n=lm]  (Bs stored [n][k])
            bf16x8 bfr = *(const bf16x8*)&Bs[(ch * 128 + f * 16 + lm) * 40 + lq * 8];
            acc[f] = __builtin_amdgcn_mfma_f32_16x16x32_bf16(af, bfr, acc[f], 0, 0, 0);
        }
    }

    // ---- epilogue: bias (C/D layout: col=lm, row=lq*4+r within 16-tile) ----
#pragma unroll
    for (int f = 0; f < 8; ++f) {
        float bb = bias[ch * 128 + f * 16 + lm];
#pragma unroll
        for (int r = 0; r < 4; ++r) acc[f][r] += bb;
    }

    // ---- partial row norms over this wave's 128 cols ----
    float s0 = 0.f, s1 = 0.f, s2 = 0.f, s3 = 0.f;
#pragma unroll
    for (int f = 0; f < 8; ++f) {
        s0 += acc[f][0] * acc[f][0];
        s1 += acc[f][1] * acc[f][1];
        s2 += acc[f][2] * acc[f][2];
        s3 += acc[f][3] * acc[f][3];
    }
#pragma unroll
    for (int m = 1; m < 16; m <<= 1) {   // reduce across the 16 col positions
        s0 += __shfl_xor(s0, m, 64);
        s1 += __shfl_xor(s1, m, 64);
        s2 += __shfl_xor(s2, m, 64);
        s3 += __shfl_xor(s3, m, 64);
    }
    if (lm == 0) {
        int rl = rg * 16 + lq * 4;
        rn2[ch][rl + 0] = s0;
        rn2[ch][rl + 1] = s1;
        rn2[ch][rl + 2] = s2;
        rn2[ch][rl + 3] = s3;
    }

    // ---- Z -> LDS (bf16) for GEMM2 ----
#pragma unroll
    for (int f = 0; f < 8; ++f) {
        int col = ch * 128 + f * 16 + lm;
#pragma unroll
        for (int r = 0; r < 4; ++r)
            Zs[(rg * 16 + lq * 4 + r) * 264 + col] = f2b(acc[f][r]);
    }
    __syncthreads();

    // ---- GEMM2: D2[class][row] = P @ Z^T, M=112 N=64 K=256 ----
    if (wave < 7) {
        floatx4 acc2[4];
#pragma unroll
        for (int nf = 0; nf < 4; ++nf) { acc2[nf][0]=0.f; acc2[nf][1]=0.f; acc2[nf][2]=0.f; acc2[nf][3]=0.f; }
        const unsigned short* gP = Pbf + (wave * 16 + lm) * DDIM + lq * 8;
#pragma unroll
        for (int ks = 0; ks < 8; ++ks) {
            bf16x8 ap = *(const bf16x8*)(gP + ks * 32);   // A[m=class][k] 16B gather (L2)
#pragma unroll
            for (int nf = 0; nf < 4; ++nf) {
                // B[k][n=row] = Z[row][k]: read Zs[row][k] contiguous in k
                bf16x8 bz = *(const bf16x8*)&Zs[(nf * 16 + lm) * 264 + ks * 32 + lq * 8];
                acc2[nf] = __builtin_amdgcn_mfma_f32_16x16x32_bf16(ap, bz, acc2[nf], 0, 0, 0);
            }
        }
        // D2 layout: col=lm -> batch row, row=lq*4+r -> 4 consecutive classes
        int c0 = wave * 16 + lq * 4;
        if (c0 < CNUM) {   // classes come in aligned groups of 4; 100%4==0
            floatx4 pn = *(const floatx4*)(pnorm2 + c0);
#pragma unroll
            for (int nf = 0; nf < 4; ++nf) {
                int rl = nf * 16 + lm;
                float rn = rn2[0][rl] + rn2[1][rl];
                floatx4 o;
#pragma unroll
                for (int r = 0; r < 4; ++r)
                    o[r] = (2.f * acc2[nf][r] - rn - pn[r]) * (1.f / 256.f);
                *(floatx4*)&out[(r0 + rl) * CNUM + c0] = o;   // 16B aligned
            }
        }
    }
}

extern "C" void kernel_launch(void* const* d_in, const int* in_sizes, int n_in,
                              void* d_out, int out_size, void* d_ws, size_t ws_size,
                              hipStream_t stream) {
    const float* x = (const float*)d_in[0];
    const float* W = (const float*)d_in[1];
    const float* b = (const float*)d_in[2];
    const float* P = (const float*)d_in[3];
    float* out = (float*)d_out;

    // ws layout: Wt bf16 [256][1024] (512 KiB) | Pbf bf16 [112][256] (56 KiB)
    //            | pnorm2 fp32 [112]  -> total ~582 KiB
    unsigned short* Wt  = (unsigned short*)d_ws;
    unsigned short* Pbf = Wt + KDIM * DDIM;
    float* pn2 = (float*)(Pbf + CPAD * DDIM);

    prep_w<<<256, 256, 0, stream>>>(W, Wt);
    prep_p<<<CPAD, 64, 0, stream>>>(P, Pbf, pn2);
    fused_main<<<BATCH / 64, 512, 0, stream>>>(x, b, Wt, Pbf, pn2, out);
}

// Round 2
// 134.134 us; speedup vs baseline: 1.0183x; 1.0183x over previous
//
#include <hip/hip_runtime.h>

// Problem constants: B=16384, IN_DIM=1024, D=256, C=100
#define BATCH 16384
#define KDIM  1024
#define DDIM  256
#define CNUM  100
#define CPAD  112   // classes padded to multiple of 16 for MFMA

typedef __bf16 bf16x4 __attribute__((ext_vector_type(4)));
typedef __bf16 bf16x8 __attribute__((ext_vector_type(8)));
typedef float  floatx4 __attribute__((ext_vector_type(4)));

static __device__ __forceinline__ unsigned short f2b(float f) {
    return __builtin_bit_cast(unsigned short, (__bf16)f);
}

// async global->LDS, 16B per lane; LDS dest = wave-uniform base + lane*16
static __device__ __forceinline__ void gload_lds16(const unsigned short* g,
                                                   unsigned short* l) {
    __builtin_amdgcn_global_load_lds(
        (const __attribute__((address_space(1))) unsigned int*)g,
        (__attribute__((address_space(3))) unsigned int*)l, 16, 0, 0);
}

// ---------------- prep (merged): W transpose->bf16, P->bf16 + pnorm2 --------
// blocks 0..255: 32x32 tile transpose of W [1024][256] -> Wt [256][1024] bf16
// blocks 256..283: 4 classes each (1/wave): P -> Pbf bf16 + ||P||^2 fp32
__global__ __launch_bounds__(256) void prep(const float* __restrict__ W,
                                            const float* __restrict__ P,
                                            unsigned short* __restrict__ Wt,
                                            unsigned short* __restrict__ Pbf,
                                            float* __restrict__ pnorm2) {
    __shared__ float T[32][33];
    const int bid = blockIdx.x;
    if (bid < 256) {
        const int k0 = (bid & 31) * 32;
        const int n0 = (bid >> 5) * 32;
        const int j  = threadIdx.x & 31;
        const int i0 = threadIdx.x >> 5;
#pragma unroll
        for (int l = 0; l < 4; ++l) {
            int i = i0 + l * 8;
            T[i][j] = W[(k0 + i) * DDIM + n0 + j];
        }
        __syncthreads();
#pragma unroll
        for (int l = 0; l < 4; ++l) {
            int i = i0 + l * 8;
            Wt[(n0 + i) * KDIM + k0 + j] = f2b(T[j][i]);
        }
    } else {
        const int wave = threadIdx.x >> 6;
        const int lane = threadIdx.x & 63;
        const int c = (bid - 256) * 4 + wave;
        float s = 0.f;
#pragma unroll
        for (int jj = 0; jj < 4; ++jj) {
            int d = jj * 64 + lane;
            float v = (c < CNUM) ? P[c * DDIM + d] : 0.f;
            Pbf[c * DDIM + d] = f2b(v);
            s += v * v;
        }
#pragma unroll
        for (int m = 1; m < 64; m <<= 1) s += __shfl_xor(s, m, 64);
        if (lane == 0) pnorm2[c] = s;
    }
}

// ---------------- fused main -------------------------------------------------
// grid = 512 blocks (BM=32 rows), 256 threads = 4 waves -> multiple blocks/CU.
// LDS union: K-loop {As[32][32], Bs[256][32]} (18.0 KB) vs epilogue Zs[32][264].
// B staged with async global_load_lds (width 16, unpadded contiguous layout).
__global__ __launch_bounds__(256, 8) void fused_main(
    const float* __restrict__ x, const float* __restrict__ bias,
    const unsigned short* __restrict__ Wt, const unsigned short* __restrict__ Pbf,
    const float* __restrict__ pnorm2, float* __restrict__ out)
{
    __shared__ unsigned short U[9216];        // 18 KB union
    unsigned short* As = U;                   // [32][32] (64 B row stride)
    unsigned short* Bs = U + 1024;            // [256][32]
    unsigned short* Zs = U;                   // [32][264] (epilogue only)
    __shared__ float rn2[2][32];

    const int tid  = threadIdx.x;
    const int wave = tid >> 6;
    const int lane = tid & 63;
    const int lm   = lane & 15;
    const int lq   = lane >> 4;
    const int rg   = wave >> 1;   // 0..1 row group (16 rows)
    const int ch   = wave & 1;    // 0..1 col half (128 cols)
    const int r0   = blockIdx.x * 32;

    // A staging: one float4 per thread per k-step
    const int rowA = tid >> 3;            // 0..31
    const int kcA  = (tid & 7) * 4;       // 0..28
    const float* gA = x + (r0 + rowA) * KDIM + kcA;

    // B staging (async): wave stages 4 chunks of 16 rows x 32 k (1 KB each)
    // lane i covers row (i>>2), shorts 8*(i&3).. within the 64 B row
    const unsigned short* gBbase = Wt + (wave * 64 + (lane >> 2)) * KDIM + (lane & 3) * 8;

    floatx4 acc[8];
#pragma unroll
    for (int f = 0; f < 8; ++f) { acc[f][0]=0.f; acc[f][1]=0.f; acc[f][2]=0.f; acc[f][3]=0.f; }

    floatx4 pa = *(const floatx4*)gA;     // prefetch A k-step 0

    for (int kk = 0; kk < KDIM; kk += 32) {
        __syncthreads();                  // prev iter frag reads done
        // issue async B tile loads (drained by the next barrier's vmcnt(0))
#pragma unroll
        for (int c = 0; c < 4; ++c)
            gload_lds16(gBbase + (c * 16) * KDIM + kk, Bs + (wave * 4 + c) * 512);
        // A: fp32 -> bf16 via registers
        bf16x4 ha;
        ha[0] = (__bf16)pa[0]; ha[1] = (__bf16)pa[1];
        ha[2] = (__bf16)pa[2]; ha[3] = (__bf16)pa[3];
        *(bf16x4*)&As[rowA * 32 + kcA] = ha;
        __syncthreads();                  // A written, B async landed
        // A-frag: A[m=lm][k=lq*8+j]
        bf16x8 af = *(const bf16x8*)&As[(rg * 16 + lm) * 32 + lq * 8];
        if (kk + 32 < KDIM)               // prefetch next A during MFMA phase
            pa = *(const floatx4*)(gA + kk + 32);
#pragma unroll
        for (int f = 0; f < 8; ++f) {
            bf16x8 bfr = *(const bf16x8*)&Bs[(ch * 128 + f * 16 + lm) * 32 + lq * 8];
            acc[f] = __builtin_amdgcn_mfma_f32_16x16x32_bf16(af, bfr, acc[f], 0, 0, 0);
        }
    }

    // ---- bias (C/D layout: col=lm, row=lq*4+r) ----
#pragma unroll
    for (int f = 0; f < 8; ++f) {
        float bb = bias[ch * 128 + f * 16 + lm];
#pragma unroll
        for (int r = 0; r < 4; ++r) acc[f][r] += bb;
    }

    // ---- partial row norms over this wave's 128 cols ----
    float s0 = 0.f, s1 = 0.f, s2 = 0.f, s3 = 0.f;
#pragma unroll
    for (int f = 0; f < 8; ++f) {
        s0 += acc[f][0] * acc[f][0];
        s1 += acc[f][1] * acc[f][1];
        s2 += acc[f][2] * acc[f][2];
        s3 += acc[f][3] * acc[f][3];
    }
#pragma unroll
    for (int m = 1; m < 16; m <<= 1) {
        s0 += __shfl_xor(s0, m, 64);
        s1 += __shfl_xor(s1, m, 64);
        s2 += __shfl_xor(s2, m, 64);
        s3 += __shfl_xor(s3, m, 64);
    }
    if (lm == 0) {
        int rl = rg * 16 + lq * 4;
        rn2[ch][rl + 0] = s0;
        rn2[ch][rl + 1] = s1;
        rn2[ch][rl + 2] = s2;
        rn2[ch][rl + 3] = s3;
    }

    __syncthreads();                      // all K-loop LDS reads done (union!)

    // ---- Z -> LDS bf16 for GEMM2 ----
#pragma unroll
    for (int f = 0; f < 8; ++f) {
        int col = ch * 128 + f * 16 + lm;
#pragma unroll
        for (int r = 0; r < 4; ++r)
            Zs[(rg * 16 + lq * 4 + r) * 264 + col] = f2b(acc[f][r]);
    }
    __syncthreads();

    // ---- GEMM2: D2[class][row] = P @ Z^T, M=112 N=32 K=256 ----
    // wave handles class-tiles {2*wave, 2*wave+1} (7 tiles total)
#pragma unroll
    for (int t = 0; t < 2; ++t) {
        const int ct = wave * 2 + t;
        if (ct < 7) {
            floatx4 acc2[2];
#pragma unroll
            for (int nf = 0; nf < 2; ++nf) { acc2[nf][0]=0.f; acc2[nf][1]=0.f; acc2[nf][2]=0.f; acc2[nf][3]=0.f; }
            const unsigned short* gP = Pbf + (ct * 16 + lm) * DDIM + lq * 8;
#pragma unroll
            for (int ks = 0; ks < 8; ++ks) {
                bf16x8 ap = *(const bf16x8*)(gP + ks * 32);   // L2-hot
#pragma unroll
                for (int nf = 0; nf < 2; ++nf) {
                    bf16x8 bz = *(const bf16x8*)&Zs[(nf * 16 + lm) * 264 + ks * 32 + lq * 8];
                    acc2[nf] = __builtin_amdgcn_mfma_f32_16x16x32_bf16(ap, bz, acc2[nf], 0, 0, 0);
                }
            }
            int c0 = ct * 16 + lq * 4;
            if (c0 < CNUM) {              // tile 6: only lq==0 (classes 96..99)
                floatx4 pn = *(const floatx4*)(pnorm2 + c0);
#pragma unroll
                for (int nf = 0; nf < 2; ++nf) {
                    int rl = nf * 16 + lm;
                    float rn = rn2[0][rl] + rn2[1][rl];
                    floatx4 o;
#pragma unroll
                    for (int r = 0; r < 4; ++r)
                        o[r] = (2.f * acc2[nf][r] - rn - pn[r]) * (1.f / 256.f);
                    *(floatx4*)&out[(r0 + rl) * CNUM + c0] = o;   // 16 B aligned
                }
            }
        }
    }
}

extern "C" void kernel_launch(void* const* d_in, const int* in_sizes, int n_in,
                              void* d_out, int out_size, void* d_ws, size_t ws_size,
                              hipStream_t stream) {
    const float* x = (const float*)d_in[0];
    const float* W = (const float*)d_in[1];
    const float* b = (const float*)d_in[2];
    const float* P = (const float*)d_in[3];
    float* out = (float*)d_out;

    // ws: Wt bf16 [256][1024] | Pbf bf16 [112][256] | pnorm2 fp32 [112]
    unsigned short* Wt  = (unsigned short*)d_ws;
    unsigned short* Pbf = Wt + KDIM * DDIM;
    float* pn2 = (float*)(Pbf + CPAD * DDIM);

    prep<<<256 + CPAD / 4, 256, 0, stream>>>(W, P, Wt, Pbf, pn2);
    fused_main<<<BATCH / 32, 256, 0, stream>>>(x, b, Wt, Pbf, pn2, out);
}